// Round 3
// baseline (247.476 us; speedup 1.0000x reference)
//
#include <hip/hip_runtime.h>

#define NT 256

// Kernel A: per-block (256-element tile) sum of seq_lengths via wave reduce.
__global__ __launch_bounds__(NT) void sum_kernel(const int* __restrict__ seq,
                                                 unsigned* __restrict__ blockSums,
                                                 int n) {
    __shared__ unsigned wsum[4];
    int tid = threadIdx.x;
    int gid = blockIdx.x * NT + tid;
    int lane = tid & 63, wave = tid >> 6;
    unsigned v = (gid < n) ? (unsigned)seq[gid] : 0u;
    #pragma unroll
    for (int off = 32; off > 0; off >>= 1) v += __shfl_down(v, off);
    if (lane == 0) wsum[wave] = v;
    __syncthreads();
    if (tid == 0) blockSums[blockIdx.x] = wsum[0] + wsum[1] + wsum[2] + wsum[3];
}

// Block-wide exclusive scan (shfl intra-wave + LDS cross-wave).
__device__ __forceinline__ unsigned block_excl_scan(unsigned v_in, int tid,
                                                    unsigned* wtot /*[4] LDS*/,
                                                    unsigned* block_total) {
    int lane = tid & 63, wave = tid >> 6;
    unsigned v = v_in;
    #pragma unroll
    for (int off = 1; off < 64; off <<= 1) {
        unsigned t = __shfl_up(v, off);
        if (lane >= off) v += t;
    }
    if (lane == 63) wtot[wave] = v;
    __syncthreads();
    unsigned woff = 0;
    #pragma unroll
    for (int w = 0; w < 4; w++) woff += (w < wave) ? wtot[w] : 0u;
    if (block_total) *block_total = wtot[0] + wtot[1] + wtot[2] + wtot[3];
    return woff + v - v_in;  // exclusive
}

// Kernel B: each block scans 256 contiguous blockSums -> group-exclusive
// offsets; writes group total. (Group offsets are reduced inside main.)
__global__ __launch_bounds__(NT) void group_scan_kernel(const unsigned* __restrict__ blockSums,
                                                        unsigned* __restrict__ blockOffsets,
                                                        unsigned* __restrict__ groupSums,
                                                        int nb) {
    __shared__ unsigned wtot[4];
    int tid = threadIdx.x;
    int i = blockIdx.x * NT + tid;
    unsigned v = (i < nb) ? blockSums[i] : 0u;
    unsigned total;
    unsigned excl = block_excl_scan(v, tid, wtot, &total);
    if (i < nb) blockOffsets[i] = excl;
    if (tid == 0) groupSums[blockIdx.x] = total;
}

// Kernel C: main compute + ordered compaction, LDS-staged xss loads.
__global__ __launch_bounds__(NT) void main_kernel(const float* __restrict__ xss,
                                                  const int* __restrict__ seq,
                                                  const float* __restrict__ Wcob,
                                                  const float* __restrict__ Wreg,
                                                  const unsigned* __restrict__ blockOffsets,
                                                  const unsigned* __restrict__ groupSums,
                                                  float* __restrict__ out,
                                                  int n) {
    // 256 elements * 21 floats (stride-21 padding: gcd(21,32)=1 -> conflict-free)
    __shared__ float sx[NT * 21];
    __shared__ unsigned wtot[4];
    __shared__ unsigned s_go;

    int tid = threadIdx.x;
    int bid = blockIdx.x;
    int gid = bid * NT + tid;

    // --- group offset: sum of groupSums[g'] for g' < (bid>>8), wave 0 only ---
    if (tid < 64) {
        int g = bid >> 8;  // ng <= 64 guaranteed (nb = 7813 -> 31 groups)
        unsigned v = (tid < g) ? groupSums[tid] : 0u;
        #pragma unroll
        for (int off = 32; off > 0; off >>= 1) v += __shfl_down(v, off);
        if (tid == 0) s_go = v;
    }

    // --- coalesced staging: 1280 float4s per block, 5 per thread ---
    {
        const float4* xv = (const float4*)xss;
        long total4 = (long)n * 5;  // n*20 floats / 4
        #pragma unroll
        for (int k = 0; k < 5; k++) {
            int gl = k * NT + tid;              // local float4 index 0..1279
            long G = (long)bid * (NT * 5) + gl; // global float4 index
            float4 v;
            if (G < total4) v = xv[G];
            else { v.x = v.y = v.z = v.w = 0.f; }
            // 20 % 4 == 0 -> each float4 lies within one element
            int le = gl / 5;        // local element
            int p4 = gl % 5;        // which float4 within element
            int w = le * 21 + p4 * 4;
            sx[w + 0] = v.x; sx[w + 1] = v.y; sx[w + 2] = v.z; sx[w + 3] = v.w;
        }
    }

    unsigned L = (gid < n) ? (unsigned)seq[gid] : 0u;

    // block scan includes a __syncthreads() that also fences sx and s_go
    unsigned excl = block_excl_scan(L, tid, wtot, nullptr);
    unsigned offset = s_go + blockOffsets[bid] + excl;

    if (gid >= n) return;

    // --- per-thread reads from LDS: stride 21, conflict-free ---
    float x[20];
    #pragma unroll
    for (int j = 0; j < 20; j++) x[j] = sx[tid * 21 + j];

    // Uniform-address weight loads -> scalar loads.
    float wc[16], wr[16];
    #pragma unroll
    for (int i = 0; i < 16; i++) { wc[i] = Wcob[i]; wr[i] = Wreg[i]; }

    // bs[s][c] = sum_f fs[s][f] * Wcob[c][f]
    float bs[4][4];
    #pragma unroll
    for (int s = 0; s < 4; s++) {
        #pragma unroll
        for (int c = 0; c < 4; c++) {
            float acc = 0.f;
            #pragma unroll
            for (int f = 0; f < 4; f++) acc += x[s * 5 + 1 + f] * wc[c * 4 + f];
            bs[s][c] = acc;
        }
    }

    // context[c] = sum_{s<L} bs[s][c] * scale[s]
    float ctx[4] = {0.f, 0.f, 0.f, 0.f};
    #pragma unroll
    for (int s = 0; s < 4; s++) {
        float m = (s < (int)L) ? x[s * 5] : 0.f;
        #pragma unroll
        for (int c = 0; c < 4; c++) ctx[c] += bs[s][c] * m;
    }

    // ys[m] = sum_c context[c] * Wreg[m][c]
    float ys[4];
    #pragma unroll
    for (int m = 0; m < 4; m++) {
        float acc = 0.f;
        #pragma unroll
        for (int c = 0; c < 4; c++) acc += ctx[c] * wr[m * 4 + c];
        ys[m] = acc;
    }

    // projs[s] = sum_m bs[s][m] * ys[m], compacted for s < L.
    #pragma unroll
    for (int s = 0; s < 4; s++) {
        if (s < (int)L) {
            float acc = 0.f;
            #pragma unroll
            for (int m = 0; m < 4; m++) acc += bs[s][m] * ys[m];
            out[offset + s] = acc;
        }
    }
}

extern "C" void kernel_launch(void* const* d_in, const int* in_sizes, int n_in,
                              void* d_out, int out_size, void* d_ws, size_t ws_size,
                              hipStream_t stream) {
    const float* xss  = (const float*)d_in[0];
    const int*   seq  = (const int*)d_in[1];
    const float* Wcob = (const float*)d_in[2];
    const float* Wreg = (const float*)d_in[3];
    float* out = (float*)d_out;

    int n  = in_sizes[1];            // B = 2,000,000
    int nb = (n + NT - 1) / NT;      // 7813 tiles
    int ng = (nb + NT - 1) / NT;     // 31 groups (<= 64 required)

    unsigned* blockSums    = (unsigned*)d_ws;
    unsigned* blockOffsets = blockSums + nb;
    unsigned* groupSums    = blockOffsets + nb;

    sum_kernel<<<nb, NT, 0, stream>>>(seq, blockSums, n);
    group_scan_kernel<<<ng, NT, 0, stream>>>(blockSums, blockOffsets, groupSums, nb);
    main_kernel<<<nb, NT, 0, stream>>>(xss, seq, Wcob, Wreg, blockOffsets, groupSums, out, n);
}